// Round 3
// baseline (914.671 us; speedup 1.0000x reference)
//
#include <hip/hip_runtime.h>
#include <hip/hip_bf16.h>

#define NPIX 16384
#define NVOC 8192

typedef short short8v __attribute__((ext_vector_type(8)));
typedef float floatx4 __attribute__((ext_vector_type(4)));

// ---- ws layout (bytes) ----
#define WS_ZEBF   0u          // 16384*256 bf16 = 8388608
#define WS_CBBF   8388608u    // 8192*256 bf16  = 4194304
#define WS_BN     12582912u   // 8192 f32
#define WS_AN     12615680u   // 16384 f32
#define WS_MIN    12681216u   // 128*16384 f32 = 8388608
#define WS_TAU    21069824u   // 16384 f32
#define WS_CNT    21135360u   // 16384 i32
#define WS_CAND   21200896u   // 16384*8 i32 = 524288
#define WS_FIDX   21725184u   // 16384 i32
#define WS_BMAX   21790720u   // 1 f32
#define WS_PART   21790976u   // 256 f32

__device__ __forceinline__ short f2bf(float v) {
  __bf16 h = (__bf16)v;
  return __builtin_bit_cast(short, h);
}

// numpy pairwise-sum of 128 squares
__device__ __forceinline__ float np_pairwise128_sq(const float* x, int stride) {
  float r[8];
#pragma unroll
  for (int j = 0; j < 8; ++j) {
    float v = x[j * stride];
    r[j] = __fmul_rn(v, v);
  }
#pragma unroll
  for (int i = 1; i < 16; ++i) {
#pragma unroll
    for (int j = 0; j < 8; ++j) {
      float v = x[(i * 8 + j) * stride];
      r[j] = __fadd_rn(r[j], __fmul_rn(v, v));
    }
  }
  return __fadd_rn(__fadd_rn(__fadd_rn(r[0], r[1]), __fadd_rn(r[2], r[3])),
                   __fadd_rn(__fadd_rn(r[4], r[5]), __fadd_rn(r[6], r[7])));
}

__global__ __launch_bounds__(256) void k_bnorm(const float* __restrict__ cb,
                                               float* __restrict__ bn) {
  __shared__ float rows[64][257];
  int tid = threadIdx.x;
  int c0 = blockIdx.x * 64;
  for (int r = 0; r < 64; ++r)
    rows[r][tid] = cb[(size_t)(c0 + r) * 256 + tid];
  __syncthreads();
  if (tid < 64) {
    float a = np_pairwise128_sq(&rows[tid][0], 1);
    float b = np_pairwise128_sq(&rows[tid][128], 1);
    bn[c0 + tid] = __fadd_rn(a, b);
  }
}

__global__ __launch_bounds__(256) void k_anorm(const float* __restrict__ ze,
                                               float* __restrict__ an) {
  int p = blockIdx.x * 256 + threadIdx.x;
  int b = p >> 10, hw = p & 1023;
  const float* base = ze + (size_t)b * 262144 + hw;
  float a = np_pairwise128_sq(base, 1024);
  float b2 = np_pairwise128_sq(base + 128 * 1024, 1024);
  an[p] = __fadd_rn(a, b2);
}

__global__ __launch_bounds__(256) void k_bmax(const float* __restrict__ bn,
                                              float* __restrict__ bmax) {
  int tid = threadIdx.x;
  float m = 0.f;
  for (int i = tid; i < NVOC; i += 256) m = fmaxf(m, bn[i]);
#pragma unroll
  for (int off = 32; off; off >>= 1) m = fmaxf(m, __shfl_xor(m, off));
  __shared__ float w4[4];
  if ((tid & 63) == 0) w4[tid >> 6] = m;
  __syncthreads();
  if (tid == 0)
    bmax[0] = sqrtf(fmaxf(fmaxf(w4[0], w4[1]), fmaxf(w4[2], w4[3])));
}

// ze [16][256][1024] fp32 -> zebf [16384][256] bf16
__global__ __launch_bounds__(256) void k_cvt_ze(const float* __restrict__ ze,
                                                short* __restrict__ zebf) {
  __shared__ short lds[64][258];
  int tid = threadIdx.x;
  int p0 = blockIdx.x * 64;
  int b = p0 >> 10, hw0 = p0 & 1023;
  const float* src = ze + (size_t)b * 262144 + hw0;
  int hw = tid & 63, c4 = tid >> 6;
#pragma unroll 4
  for (int i = 0; i < 64; ++i) {
    int c = i * 4 + c4;
    lds[hw][c] = f2bf(src[(size_t)c * 1024 + hw]);
  }
  __syncthreads();
  int row = tid >> 2, q = tid & 3;
  short* dst = zebf + (size_t)(p0 + row) * 256 + q * 64;
#pragma unroll
  for (int s = 0; s < 8; ++s) {
    short8v v;
#pragma unroll
    for (int e = 0; e < 8; ++e) v[e] = lds[row][q * 64 + s * 8 + e];
    *reinterpret_cast<short8v*>(dst + s * 8) = v;
  }
}

__global__ __launch_bounds__(256) void k_cvt_cb(const float* __restrict__ cb,
                                                short* __restrict__ cbbf) {
  size_t i = ((size_t)blockIdx.x * 256 + threadIdx.x) * 8;
  float4 a = *reinterpret_cast<const float4*>(cb + i);
  float4 b = *reinterpret_cast<const float4*>(cb + i + 4);
  short8v v;
  v[0] = f2bf(a.x); v[1] = f2bf(a.y); v[2] = f2bf(a.z); v[3] = f2bf(a.w);
  v[4] = f2bf(b.x); v[5] = f2bf(b.y); v[6] = f2bf(b.z); v[7] = f2bf(b.w);
  *reinterpret_cast<short8v*>(cbbf + i) = v;
}

// Single-pass bf16 MFMA distance GEMM, 256x256 tile, 8 waves (2Mx4N),
// per-wave 128x64, BK=64 double-buffered. Epilogue: per-pixel min over each
// wave's 64 codes -> wsmin[128 colblocks][NPIX].
__global__ __launch_bounds__(512, 2) void k_gemm(const short* __restrict__ zebf,
                                                 const short* __restrict__ cbbf,
                                                 const float* __restrict__ bn,
                                                 float* __restrict__ wsmin) {
  __shared__ short As[2][16384];
  __shared__ short Bs[2][16384];
  int tid = threadIdx.x;
  int lane = tid & 63, w = tid >> 6;
  int wr = w >> 2, wc = w & 3;
  int g = lane >> 4, r16 = lane & 15;
  // bijective XCD swizzle (2048 % 8 == 0)
  int swz = (blockIdx.x & 7) * 256 + (blockIdx.x >> 3);
  int mb = swz & 63, nb = swz >> 6;
  int p0 = mb * 256, n0 = nb * 256;

  floatx4 acc[8][4];
#pragma unroll
  for (int i = 0; i < 8; ++i)
#pragma unroll
    for (int j = 0; j < 4; ++j) acc[i][j] = floatx4{0.f, 0.f, 0.f, 0.f};

  const short* Aq = zebf + (size_t)p0 * 256;
  const short* Bq = cbbf + (size_t)n0 * 256;

  short8v ra[4], rb[4];
  int srow[4], sc16[4];
#pragma unroll
  for (int s = 0; s < 4; ++s) {
    int cid = tid + s * 512;
    srow[s] = cid >> 3;
    sc16[s] = cid & 7;
  }

#define LOADK(kt)                                                              \
  {                                                                            \
    _Pragma("unroll") for (int s = 0; s < 4; ++s) {                            \
      ra[s] = *reinterpret_cast<const short8v*>(                               \
          Aq + (size_t)srow[s] * 256 + (kt) * 64 + sc16[s] * 8);               \
      rb[s] = *reinterpret_cast<const short8v*>(                               \
          Bq + (size_t)srow[s] * 256 + (kt) * 64 + sc16[s] * 8);               \
    }                                                                          \
  }
#define STOREK(bufi)                                                           \
  {                                                                            \
    _Pragma("unroll") for (int s = 0; s < 4; ++s) {                            \
      int off = srow[s] * 64 + ((sc16[s] ^ (srow[s] & 7)) * 8);                \
      *reinterpret_cast<short8v*>(&As[bufi][off]) = ra[s];                     \
      *reinterpret_cast<short8v*>(&Bs[bufi][off]) = rb[s];                     \
    }                                                                          \
  }

  LOADK(0);
  STOREK(0);
  __syncthreads();

  for (int kt = 0; kt < 4; ++kt) {
    int cur = kt & 1;
    if (kt < 3) LOADK(kt + 1);  // issue-early; lands under MFMA
#pragma unroll
    for (int ks = 0; ks < 2; ++ks) {
      short8v af[8], bfv[4];
      int c16 = ks * 4 + g;
#pragma unroll
      for (int rf = 0; rf < 8; ++rf) {
        int row = wr * 128 + rf * 16 + r16;
        af[rf] = *reinterpret_cast<const short8v*>(
            &As[cur][row * 64 + ((c16 ^ (row & 7)) * 8)]);
      }
#pragma unroll
      for (int cf = 0; cf < 4; ++cf) {
        int col = wc * 64 + cf * 16 + r16;
        bfv[cf] = *reinterpret_cast<const short8v*>(
            &Bs[cur][col * 64 + ((c16 ^ (col & 7)) * 8)]);
      }
      __builtin_amdgcn_s_setprio(1);
#pragma unroll
      for (int rf = 0; rf < 8; ++rf)
#pragma unroll
        for (int cf = 0; cf < 4; ++cf)
          acc[rf][cf] = __builtin_amdgcn_mfma_f32_16x16x32_bf16(
              af[rf], bfv[cf], acc[rf][cf], 0, 0, 0);
      __builtin_amdgcn_s_setprio(0);
    }
    if (kt < 3) STOREK(cur ^ 1);  // write-late into the other buffer
    __syncthreads();
  }

  // epilogue: t_hat = bn[j] - 2*dot ; per-pixel min over this wave's 64 cols
  float Bj[4];
#pragma unroll
  for (int cf = 0; cf < 4; ++cf) Bj[cf] = bn[n0 + wc * 64 + cf * 16 + r16];
  float* wout = wsmin + (size_t)(nb * 4 + wc) * NPIX + p0;
#pragma unroll
  for (int rf = 0; rf < 8; ++rf) {
    float rowmin[4];
#pragma unroll
    for (int rr = 0; rr < 4; ++rr) {
      float mv = 3.4e38f;
#pragma unroll
      for (int cf = 0; cf < 4; ++cf)
        mv = fminf(mv, __builtin_fmaf(-2.0f, acc[rf][cf][rr], Bj[cf]));
      rowmin[rr] = mv;
    }
#pragma unroll
    for (int off = 1; off < 16; off <<= 1)
#pragma unroll
      for (int rr = 0; rr < 4; ++rr)
        rowmin[rr] = fminf(rowmin[rr], __shfl_xor(rowmin[rr], off, 16));
    if (r16 == 0) {
#pragma unroll
      for (int rr = 0; rr < 4; ++rr)
        wout[wr * 128 + rf * 16 + g * 4 + rr] = rowmin[rr];
    }
  }
#undef LOADK
#undef STOREK
}

// per-pixel global approx min -> tau; flag colblocks with blockmin <= tau
__global__ __launch_bounds__(256) void k_reduce(const float* __restrict__ wsmin,
                                                const float* __restrict__ an,
                                                const float* __restrict__ bmax,
                                                float* __restrict__ tau,
                                                int* __restrict__ cnt,
                                                int* __restrict__ cand) {
  int p = blockIdx.x * 256 + threadIdx.x;
  float mv = 3.4e38f;
#pragma unroll 8
  for (int c = 0; c < 128; ++c) mv = fminf(mv, wsmin[(size_t)c * NPIX + p]);
  float tp = mv + 0.017f * sqrtf(an[p]) * bmax[0] + 2e-4f;
  tau[p] = tp;
  int n = 0;
  for (int c = 0; c < 128; ++c) {
    if (wsmin[(size_t)c * NPIX + p] <= tp) {
      if (n < 8) cand[p * 8 + n] = c;
      ++n;
    }
  }
  cnt[p] = n;
}

// exact fp32 rescore: one wave per pixel; for each flagged 64-code block,
// lane owns one code and replicates round-1's exact arithmetic.
__global__ __launch_bounds__(256) void k_rescore(const float* __restrict__ ze,
                                                 const float* __restrict__ cb,
                                                 const float* __restrict__ an,
                                                 const float* __restrict__ bn,
                                                 const int* __restrict__ cnt,
                                                 const int* __restrict__ cand,
                                                 int* __restrict__ fidx) {
  __shared__ float zl[4][256];
  int tid = threadIdx.x;
  int wv = tid >> 6, lane = tid & 63;
  int p = blockIdx.x * 4 + wv;
  int b = p >> 10, hw = p & 1023;
  const float* zr = ze + (size_t)b * 262144 + hw;
#pragma unroll
  for (int i = 0; i < 4; ++i) {
    int c = lane * 4 + i;
    zl[wv][c] = zr[(size_t)c * 1024];
  }
  __syncthreads();
  float ap = an[p];
  int nf = cnt[p];
  float bestd = 3.4e38f;
  int besti = 0x7fffffff;
  int nloop = (nf <= 8) ? nf : 128;
  for (int f = 0; f < nloop; ++f) {
    int fb = (nf <= 8) ? cand[p * 8 + f] : f;
    int j = fb * 64 + lane;
    const float* cr = cb + (size_t)j * 256;
    float acc = 0.f;
#pragma unroll 8
    for (int k4 = 0; k4 < 64; ++k4) {
      float4 cv = *reinterpret_cast<const float4*>(cr + k4 * 4);
      const float* zv = &zl[wv][k4 * 4];
      acc = __builtin_fmaf(zv[0], cv.x, acc);
      acc = __builtin_fmaf(zv[1], cv.y, acc);
      acc = __builtin_fmaf(zv[2], cv.z, acc);
      acc = __builtin_fmaf(zv[3], cv.w, acc);
    }
    float d = __fsub_rn(__fadd_rn(ap, bn[j]), 2.0f * acc);
    if (d < bestd || (d == bestd && j < besti)) { bestd = d; besti = j; }
  }
#pragma unroll
  for (int off = 1; off < 64; off <<= 1) {
    float d2 = __shfl_xor(bestd, off);
    int i2 = __shfl_xor(besti, off);
    if (d2 < bestd || (d2 == bestd && i2 < besti)) { bestd = d2; besti = i2; }
  }
  if (lane == 0) fidx[p] = besti;
}

__global__ __launch_bounds__(256) void k_gather(const float* __restrict__ ze,
                                                const float* __restrict__ cb,
                                                const int* __restrict__ fidx,
                                                float* __restrict__ out_zq,
                                                float* __restrict__ out_idx,
                                                float* __restrict__ part) {
  __shared__ float qrow[64][257];
  __shared__ int sidx[64];
  int tid = threadIdx.x;
  int p0 = blockIdx.x * 64;
  int b = p0 >> 10, hw0 = p0 & 1023;
  if (tid < 64) {
    int bi = fidx[p0 + tid];
    sidx[tid] = bi;
    out_idx[p0 + tid] = (float)bi;
  }
  __syncthreads();
  for (int r = 0; r < 64; ++r)
    qrow[r][tid] = cb[(size_t)sidx[r] * 256 + tid];
  __syncthreads();
  float lsum = 0.f;
  size_t zbase = (size_t)b * 262144 + hw0;
#pragma unroll 4
  for (int i = 0; i < 64; ++i) {
    int px = tid & 63;
    int c = i * 4 + (tid >> 6);
    float qv = qrow[px][c];
    size_t gi = zbase + (size_t)c * 1024 + px;
    float zev = ze[gi];
    out_zq[gi] = __fadd_rn(zev, __fsub_rn(qv, zev));
    float d = zev - qv;
    lsum = __builtin_fmaf(d, d, lsum);
  }
#pragma unroll
  for (int off = 32; off; off >>= 1) lsum += __shfl_xor(lsum, off, 64);
  __shared__ float wsum[4];
  if ((tid & 63) == 0) wsum[tid >> 6] = lsum;
  __syncthreads();
  if (tid == 0) part[blockIdx.x] = (wsum[0] + wsum[1]) + (wsum[2] + wsum[3]);
}

__global__ __launch_bounds__(256) void k_final(const float* __restrict__ part,
                                               float* __restrict__ out0) {
  int tid = threadIdx.x;
  float s = part[tid];
#pragma unroll
  for (int off = 32; off; off >>= 1) s += __shfl_xor(s, off, 64);
  __shared__ float wsum[4];
  if ((tid & 63) == 0) wsum[tid >> 6] = s;
  __syncthreads();
  if (tid == 0)
    out0[0] = 1.25f * ((wsum[0] + wsum[1]) + (wsum[2] + wsum[3])) / 4194304.0f;
}

extern "C" void kernel_launch(void* const* d_in, const int* in_sizes, int n_in,
                              void* d_out, int out_size, void* d_ws, size_t ws_size,
                              hipStream_t stream) {
  const float* ze = (const float*)d_in[0];
  const float* cb = (const float*)d_in[1];
  float* out = (float*)d_out;
  char* ws = (char*)d_ws;
  short* zebf = (short*)(ws + WS_ZEBF);
  short* cbbf = (short*)(ws + WS_CBBF);
  float* bn = (float*)(ws + WS_BN);
  float* an = (float*)(ws + WS_AN);
  float* wsmin = (float*)(ws + WS_MIN);
  float* tau = (float*)(ws + WS_TAU);
  int* cnt = (int*)(ws + WS_CNT);
  int* cand = (int*)(ws + WS_CAND);
  int* fidx = (int*)(ws + WS_FIDX);
  float* bmax = (float*)(ws + WS_BMAX);
  float* part = (float*)(ws + WS_PART);
  float* out_loss = out;
  float* out_zq = out + 1;
  float* out_idx = out + 1 + 4194304;

  k_cvt_ze<<<256, 256, 0, stream>>>(ze, zebf);
  k_cvt_cb<<<1024, 256, 0, stream>>>(cb, cbbf);
  k_bnorm<<<128, 256, 0, stream>>>(cb, bn);
  k_anorm<<<64, 256, 0, stream>>>(ze, an);
  k_bmax<<<1, 256, 0, stream>>>(bn, bmax);
  k_gemm<<<2048, 512, 0, stream>>>(zebf, cbbf, bn, wsmin);
  k_reduce<<<64, 256, 0, stream>>>(wsmin, an, bmax, tau, cnt, cand);
  k_rescore<<<4096, 256, 0, stream>>>(ze, cb, an, bn, cnt, cand, fidx);
  k_gather<<<256, 256, 0, stream>>>(ze, cb, fidx, out_zq, out_idx, part);
  k_final<<<1, 256, 0, stream>>>(part, out_loss);
}

// Round 4
// 373.928 us; speedup vs baseline: 2.4461x; 2.4461x over previous
//
#include <hip/hip_runtime.h>
#include <hip/hip_bf16.h>

#define NPIX 16384
#define NVOC 8192

typedef short short8v __attribute__((ext_vector_type(8)));
typedef float floatx4 __attribute__((ext_vector_type(4)));

// ---- ws layout (bytes) ----
#define WS_ZEBF   0u          // 16384*256 bf16 = 8388608
#define WS_CBBF   8388608u    // 8192*256 bf16  = 4194304
#define WS_BN     12582912u   // 8192 f32
#define WS_AN     12615680u   // 16384 f32
#define WS_MIN    12681216u   // 128*16384 f32 = 8388608
#define WS_TAU    21069824u   // 16384 f32
#define WS_CNT    21135360u   // 16384 i32
#define WS_CAND   21200896u   // 16384*16 i32 = 1048576
#define WS_FIDX   22249472u   // 16384 i32
#define WS_BMAX   22315008u   // 1 f32
#define WS_PART   22315264u   // 256 f32

__device__ __forceinline__ short f2bf(float v) {
  __bf16 h = (__bf16)v;
  return __builtin_bit_cast(short, h);
}

// numpy pairwise-sum of 128 squares
__device__ __forceinline__ float np_pairwise128_sq(const float* x, int stride) {
  float r[8];
#pragma unroll
  for (int j = 0; j < 8; ++j) {
    float v = x[j * stride];
    r[j] = __fmul_rn(v, v);
  }
#pragma unroll
  for (int i = 1; i < 16; ++i) {
#pragma unroll
    for (int j = 0; j < 8; ++j) {
      float v = x[(i * 8 + j) * stride];
      r[j] = __fadd_rn(r[j], __fmul_rn(v, v));
    }
  }
  return __fadd_rn(__fadd_rn(__fadd_rn(r[0], r[1]), __fadd_rn(r[2], r[3])),
                   __fadd_rn(__fadd_rn(r[4], r[5]), __fadd_rn(r[6], r[7])));
}

__global__ __launch_bounds__(256) void k_bnorm(const float* __restrict__ cb,
                                               float* __restrict__ bn) {
  __shared__ float rows[64][257];
  int tid = threadIdx.x;
  int c0 = blockIdx.x * 64;
  for (int r = 0; r < 64; ++r)
    rows[r][tid] = cb[(size_t)(c0 + r) * 256 + tid];
  __syncthreads();
  if (tid < 64) {
    float a = np_pairwise128_sq(&rows[tid][0], 1);
    float b = np_pairwise128_sq(&rows[tid][128], 1);
    bn[c0 + tid] = __fadd_rn(a, b);
  }
}

__global__ __launch_bounds__(256) void k_anorm(const float* __restrict__ ze,
                                               float* __restrict__ an) {
  int p = blockIdx.x * 256 + threadIdx.x;
  int b = p >> 10, hw = p & 1023;
  const float* base = ze + (size_t)b * 262144 + hw;
  float a = np_pairwise128_sq(base, 1024);
  float b2 = np_pairwise128_sq(base + 128 * 1024, 1024);
  an[p] = __fadd_rn(a, b2);
}

__global__ __launch_bounds__(256) void k_bmax(const float* __restrict__ bn,
                                              float* __restrict__ bmax) {
  int tid = threadIdx.x;
  float m = 0.f;
  for (int i = tid; i < NVOC; i += 256) m = fmaxf(m, bn[i]);
#pragma unroll
  for (int off = 32; off; off >>= 1) m = fmaxf(m, __shfl_xor(m, off));
  __shared__ float w4[4];
  if ((tid & 63) == 0) w4[tid >> 6] = m;
  __syncthreads();
  if (tid == 0)
    bmax[0] = sqrtf(fmaxf(fmaxf(w4[0], w4[1]), fmaxf(w4[2], w4[3])));
}

// ze [16][256][1024] fp32 -> zebf [16384][256] bf16
__global__ __launch_bounds__(256) void k_cvt_ze(const float* __restrict__ ze,
                                                short* __restrict__ zebf) {
  __shared__ short lds[64][258];
  int tid = threadIdx.x;
  int p0 = blockIdx.x * 64;
  int b = p0 >> 10, hw0 = p0 & 1023;
  const float* src = ze + (size_t)b * 262144 + hw0;
  int hw = tid & 63, c4 = tid >> 6;
#pragma unroll 4
  for (int i = 0; i < 64; ++i) {
    int c = i * 4 + c4;
    lds[hw][c] = f2bf(src[(size_t)c * 1024 + hw]);
  }
  __syncthreads();
  int row = tid >> 2, q = tid & 3;
  short* dst = zebf + (size_t)(p0 + row) * 256 + q * 64;
#pragma unroll
  for (int s = 0; s < 8; ++s) {
    short8v v;
#pragma unroll
    for (int e = 0; e < 8; ++e) v[e] = lds[row][q * 64 + s * 8 + e];
    *reinterpret_cast<short8v*>(dst + s * 8) = v;
  }
}

__global__ __launch_bounds__(256) void k_cvt_cb(const float* __restrict__ cb,
                                                short* __restrict__ cbbf) {
  size_t i = ((size_t)blockIdx.x * 256 + threadIdx.x) * 8;
  float4 a = *reinterpret_cast<const float4*>(cb + i);
  float4 b = *reinterpret_cast<const float4*>(cb + i + 4);
  short8v v;
  v[0] = f2bf(a.x); v[1] = f2bf(a.y); v[2] = f2bf(a.z); v[3] = f2bf(a.w);
  v[4] = f2bf(b.x); v[5] = f2bf(b.y); v[6] = f2bf(b.z); v[7] = f2bf(b.w);
  *reinterpret_cast<short8v*>(cbbf + i) = v;
}

// Single-pass bf16 MFMA distance GEMM, 256x256 tile, 8 waves (2Mx4N),
// per-wave 128x64, BK=64 double-buffered. Epilogue: per-pixel min over each
// wave's 64 codes -> wsmin[128 colblocks][NPIX].
__global__ __launch_bounds__(512, 2) void k_gemm(const short* __restrict__ zebf,
                                                 const short* __restrict__ cbbf,
                                                 const float* __restrict__ bn,
                                                 float* __restrict__ wsmin) {
  __shared__ short As[2][16384];
  __shared__ short Bs[2][16384];
  int tid = threadIdx.x;
  int lane = tid & 63, w = tid >> 6;
  int wr = w >> 2, wc = w & 3;
  int g = lane >> 4, r16 = lane & 15;
  // bijective XCD swizzle (2048 % 8 == 0)
  int swz = (blockIdx.x & 7) * 256 + (blockIdx.x >> 3);
  int mb = swz & 63, nb = swz >> 6;
  int p0 = mb * 256, n0 = nb * 256;

  floatx4 acc[8][4];
#pragma unroll
  for (int i = 0; i < 8; ++i)
#pragma unroll
    for (int j = 0; j < 4; ++j) acc[i][j] = floatx4{0.f, 0.f, 0.f, 0.f};

  const short* Aq = zebf + (size_t)p0 * 256;
  const short* Bq = cbbf + (size_t)n0 * 256;

  short8v ra[4], rb[4];
  int srow[4], sc16[4];
#pragma unroll
  for (int s = 0; s < 4; ++s) {
    int cid = tid + s * 512;
    srow[s] = cid >> 3;
    sc16[s] = cid & 7;
  }

#define LOADK(kt)                                                              \
  {                                                                            \
    _Pragma("unroll") for (int s = 0; s < 4; ++s) {                            \
      ra[s] = *reinterpret_cast<const short8v*>(                               \
          Aq + (size_t)srow[s] * 256 + (kt) * 64 + sc16[s] * 8);               \
      rb[s] = *reinterpret_cast<const short8v*>(                               \
          Bq + (size_t)srow[s] * 256 + (kt) * 64 + sc16[s] * 8);               \
    }                                                                          \
  }
#define STOREK(bufi)                                                           \
  {                                                                            \
    _Pragma("unroll") for (int s = 0; s < 4; ++s) {                            \
      int off = srow[s] * 64 + ((sc16[s] ^ (srow[s] & 7)) * 8);                \
      *reinterpret_cast<short8v*>(&As[bufi][off]) = ra[s];                     \
      *reinterpret_cast<short8v*>(&Bs[bufi][off]) = rb[s];                     \
    }                                                                          \
  }

  LOADK(0);
  STOREK(0);
  __syncthreads();

  for (int kt = 0; kt < 4; ++kt) {
    int cur = kt & 1;
    if (kt < 3) LOADK(kt + 1);  // issue-early; lands under MFMA
#pragma unroll
    for (int ks = 0; ks < 2; ++ks) {
      short8v af[8], bfv[4];
      int c16 = ks * 4 + g;
#pragma unroll
      for (int rf = 0; rf < 8; ++rf) {
        int row = wr * 128 + rf * 16 + r16;
        af[rf] = *reinterpret_cast<const short8v*>(
            &As[cur][row * 64 + ((c16 ^ (row & 7)) * 8)]);
      }
#pragma unroll
      for (int cf = 0; cf < 4; ++cf) {
        int col = wc * 64 + cf * 16 + r16;
        bfv[cf] = *reinterpret_cast<const short8v*>(
            &Bs[cur][col * 64 + ((c16 ^ (col & 7)) * 8)]);
      }
      __builtin_amdgcn_s_setprio(1);
#pragma unroll
      for (int rf = 0; rf < 8; ++rf)
#pragma unroll
        for (int cf = 0; cf < 4; ++cf)
          acc[rf][cf] = __builtin_amdgcn_mfma_f32_16x16x32_bf16(
              af[rf], bfv[cf], acc[rf][cf], 0, 0, 0);
      __builtin_amdgcn_s_setprio(0);
    }
    if (kt < 3) STOREK(cur ^ 1);  // write-late into the other buffer
    __syncthreads();
  }

  // epilogue: t_hat = bn[j] - 2*dot ; per-pixel min over this wave's 64 cols
  float Bj[4];
#pragma unroll
  for (int cf = 0; cf < 4; ++cf) Bj[cf] = bn[n0 + wc * 64 + cf * 16 + r16];
  float* wout = wsmin + (size_t)(nb * 4 + wc) * NPIX + p0;
#pragma unroll
  for (int rf = 0; rf < 8; ++rf) {
    float rowmin[4];
#pragma unroll
    for (int rr = 0; rr < 4; ++rr) {
      float mv = 3.4e38f;
#pragma unroll
      for (int cf = 0; cf < 4; ++cf)
        mv = fminf(mv, __builtin_fmaf(-2.0f, acc[rf][cf][rr], Bj[cf]));
      rowmin[rr] = mv;
    }
#pragma unroll
    for (int off = 1; off < 16; off <<= 1)
#pragma unroll
      for (int rr = 0; rr < 4; ++rr)
        rowmin[rr] = fminf(rowmin[rr], __shfl_xor(rowmin[rr], off, 16));
    if (r16 == 0) {
#pragma unroll
      for (int rr = 0; rr < 4; ++rr)
        wout[wr * 128 + rf * 16 + g * 4 + rr] = rowmin[rr];
    }
  }
#undef LOADK
#undef STOREK
}

// per-pixel global approx min -> tau; flag colblocks with blockmin <= tau
__global__ __launch_bounds__(256) void k_reduce(const float* __restrict__ wsmin,
                                                const float* __restrict__ an,
                                                const float* __restrict__ bmax,
                                                float* __restrict__ tau,
                                                int* __restrict__ cnt,
                                                int* __restrict__ cand) {
  int p = blockIdx.x * 256 + threadIdx.x;
  float mv = 3.4e38f;
#pragma unroll 8
  for (int c = 0; c < 128; ++c) mv = fminf(mv, wsmin[(size_t)c * NPIX + p]);
  float tp = mv + 0.017f * sqrtf(an[p]) * bmax[0] + 2e-4f;
  tau[p] = tp;
  int n = 0;
  for (int c = 0; c < 128; ++c) {
    if (wsmin[(size_t)c * NPIX + p] <= tp) {
      if (n < 16) cand[p * 16 + n] = c;
      ++n;
    }
  }
  cnt[p] = n;
}

// exact fp32 rescore, coalesced: one workgroup per pixel. For each flagged
// 64-code block, wave wv owns codes [wv*16, wv*16+16) in ascending j; all 64
// lanes cooperatively read each code's row (float4 per lane = coalesced 1KB),
// butterfly-reduce the dot (deterministic order), tie-break by global j.
__global__ __launch_bounds__(256) void k_rescore(const float* __restrict__ ze,
                                                 const float* __restrict__ cb,
                                                 const float* __restrict__ an,
                                                 const float* __restrict__ bn,
                                                 const int* __restrict__ cnt,
                                                 const int* __restrict__ cand,
                                                 int* __restrict__ fidx) {
  __shared__ float zlds[256];
  __shared__ float wbest[4];
  __shared__ int wbi[4];
  int tid = threadIdx.x;
  int p = blockIdx.x;
  int b = p >> 10, hw = p & 1023;
  const float* zr = ze + (size_t)b * 262144 + hw;
  zlds[tid] = zr[(size_t)tid * 1024];
  __syncthreads();
  int lane = tid & 63, wv = tid >> 6;
  float4 z4 = *reinterpret_cast<const float4*>(&zlds[lane * 4]);
  float ap = an[p];
  int nf = cnt[p];
  float bestd = 3.4e38f;
  int besti = 0x7fffffff;
  int nloop = (nf <= 16) ? nf : 128;
  for (int f = 0; f < nloop; ++f) {
    int fb = (nf <= 16) ? cand[p * 16 + f] : f;
    int jbase = fb * 64 + wv * 16;
#pragma unroll 4
    for (int i = 0; i < 16; ++i) {
      int j = jbase + i;
      float4 cv =
          *reinterpret_cast<const float4*>(cb + (size_t)j * 256 + lane * 4);
      float s = __fmul_rn(z4.x, cv.x);
      s = __builtin_fmaf(z4.y, cv.y, s);
      s = __builtin_fmaf(z4.z, cv.z, s);
      s = __builtin_fmaf(z4.w, cv.w, s);
#pragma unroll
      for (int off = 1; off < 64; off <<= 1) s += __shfl_xor(s, off);
      float d = __fsub_rn(__fadd_rn(ap, bn[j]), 2.0f * s);
      if (d < bestd || (d == bestd && j < besti)) { bestd = d; besti = j; }
    }
  }
  if (lane == 0) { wbest[wv] = bestd; wbi[wv] = besti; }
  __syncthreads();
  if (tid == 0) {
    float bd = wbest[0];
    int bi = wbi[0];
#pragma unroll
    for (int w2 = 1; w2 < 4; ++w2) {
      if (wbest[w2] < bd || (wbest[w2] == bd && wbi[w2] < bi)) {
        bd = wbest[w2];
        bi = wbi[w2];
      }
    }
    fidx[p] = bi;
  }
}

__global__ __launch_bounds__(256) void k_gather(const float* __restrict__ ze,
                                                const float* __restrict__ cb,
                                                const int* __restrict__ fidx,
                                                float* __restrict__ out_zq,
                                                float* __restrict__ out_idx,
                                                float* __restrict__ part) {
  __shared__ float qrow[64][257];
  __shared__ int sidx[64];
  int tid = threadIdx.x;
  int p0 = blockIdx.x * 64;
  int b = p0 >> 10, hw0 = p0 & 1023;
  if (tid < 64) {
    int bi = fidx[p0 + tid];
    sidx[tid] = bi;
    out_idx[p0 + tid] = (float)bi;
  }
  __syncthreads();
  for (int r = 0; r < 64; ++r)
    qrow[r][tid] = cb[(size_t)sidx[r] * 256 + tid];
  __syncthreads();
  float lsum = 0.f;
  size_t zbase = (size_t)b * 262144 + hw0;
#pragma unroll 4
  for (int i = 0; i < 64; ++i) {
    int px = tid & 63;
    int c = i * 4 + (tid >> 6);
    float qv = qrow[px][c];
    size_t gi = zbase + (size_t)c * 1024 + px;
    float zev = ze[gi];
    out_zq[gi] = __fadd_rn(zev, __fsub_rn(qv, zev));
    float d = zev - qv;
    lsum = __builtin_fmaf(d, d, lsum);
  }
#pragma unroll
  for (int off = 32; off; off >>= 1) lsum += __shfl_xor(lsum, off, 64);
  __shared__ float wsum[4];
  if ((tid & 63) == 0) wsum[tid >> 6] = lsum;
  __syncthreads();
  if (tid == 0) part[blockIdx.x] = (wsum[0] + wsum[1]) + (wsum[2] + wsum[3]);
}

__global__ __launch_bounds__(256) void k_final(const float* __restrict__ part,
                                               float* __restrict__ out0) {
  int tid = threadIdx.x;
  float s = part[tid];
#pragma unroll
  for (int off = 32; off; off >>= 1) s += __shfl_xor(s, off, 64);
  __shared__ float wsum[4];
  if ((tid & 63) == 0) wsum[tid >> 6] = s;
  __syncthreads();
  if (tid == 0)
    out0[0] = 1.25f * ((wsum[0] + wsum[1]) + (wsum[2] + wsum[3])) / 4194304.0f;
}

extern "C" void kernel_launch(void* const* d_in, const int* in_sizes, int n_in,
                              void* d_out, int out_size, void* d_ws, size_t ws_size,
                              hipStream_t stream) {
  const float* ze = (const float*)d_in[0];
  const float* cb = (const float*)d_in[1];
  float* out = (float*)d_out;
  char* ws = (char*)d_ws;
  short* zebf = (short*)(ws + WS_ZEBF);
  short* cbbf = (short*)(ws + WS_CBBF);
  float* bn = (float*)(ws + WS_BN);
  float* an = (float*)(ws + WS_AN);
  float* wsmin = (float*)(ws + WS_MIN);
  float* tau = (float*)(ws + WS_TAU);
  int* cnt = (int*)(ws + WS_CNT);
  int* cand = (int*)(ws + WS_CAND);
  int* fidx = (int*)(ws + WS_FIDX);
  float* bmax = (float*)(ws + WS_BMAX);
  float* part = (float*)(ws + WS_PART);
  float* out_loss = out;
  float* out_zq = out + 1;
  float* out_idx = out + 1 + 4194304;

  k_cvt_ze<<<256, 256, 0, stream>>>(ze, zebf);
  k_cvt_cb<<<1024, 256, 0, stream>>>(cb, cbbf);
  k_bnorm<<<128, 256, 0, stream>>>(cb, bn);
  k_anorm<<<64, 256, 0, stream>>>(ze, an);
  k_bmax<<<1, 256, 0, stream>>>(bn, bmax);
  k_gemm<<<2048, 512, 0, stream>>>(zebf, cbbf, bn, wsmin);
  k_reduce<<<64, 256, 0, stream>>>(wsmin, an, bmax, tau, cnt, cand);
  k_rescore<<<16384, 256, 0, stream>>>(ze, cb, an, bn, cnt, cand, fidx);
  k_gather<<<256, 256, 0, stream>>>(ze, cb, fidx, out_zq, out_idx, part);
  k_final<<<1, 256, 0, stream>>>(part, out_loss);
}

// Round 5
// 280.602 us; speedup vs baseline: 3.2597x; 1.3326x over previous
//
#include <hip/hip_runtime.h>
#include <hip/hip_bf16.h>

#define NPIX 16384
#define NVOC 8192
#define BCAP 8192
#define CHUNK 128

typedef short short8v __attribute__((ext_vector_type(8)));
typedef float floatx4 __attribute__((ext_vector_type(4)));

// ---- ws layout (bytes) ----
// region A: zebf during cvt/gemm, then reused for bucket/result arrays
#define WS_ZEBF   0u          // 16384*256 bf16 = 8388608 (dead after k_gemm)
#define WS_BLIST  0u          // 128*8192 i32 = 4194304   (alias, post-gemm)
#define WS_CAND   4194304u    // 16384*16 i32 = 1048576
#define WS_CNT    5242880u    // 16384 i32
#define WS_PK     5308416u    // 16384 u64 = 131072
#define WS_OVF    5439488u    // 16384 i32
#define WS_BCNT   5505024u    // 128 i32 (pad)
// region B: persistent
#define WS_CBBF   8388608u    // 8192*256 bf16 = 4194304
#define WS_ZEF    12582912u   // 16384*256 f32 = 16777216
#define WS_MIN    29360128u   // 128*16384 f32 = 8388608
#define WS_BN     37748736u   // 8192 f32
#define WS_AN     37781504u   // 16384 f32
#define WS_BMAX   37847040u   // 1 f32
#define WS_PART   37847296u   // 256 f32

__device__ __forceinline__ short f2bf(float v) {
  __bf16 h = (__bf16)v;
  return __builtin_bit_cast(short, h);
}

__device__ __forceinline__ float rl(float v, int l) {
  return __uint_as_float(__builtin_amdgcn_readlane(__float_as_uint(v), l));
}

__device__ __forceinline__ unsigned long long packdj(float d, int j) {
  return ((unsigned long long)__float_as_uint(d) << 32) | (unsigned int)j;
}

// numpy pairwise-sum of 128 squares
__device__ __forceinline__ float np_pairwise128_sq(const float* x, int stride) {
  float r[8];
#pragma unroll
  for (int j = 0; j < 8; ++j) {
    float v = x[j * stride];
    r[j] = __fmul_rn(v, v);
  }
#pragma unroll
  for (int i = 1; i < 16; ++i) {
#pragma unroll
    for (int j = 0; j < 8; ++j) {
      float v = x[(i * 8 + j) * stride];
      r[j] = __fadd_rn(r[j], __fmul_rn(v, v));
    }
  }
  return __fadd_rn(__fadd_rn(__fadd_rn(r[0], r[1]), __fadd_rn(r[2], r[3])),
                   __fadd_rn(__fadd_rn(r[4], r[5]), __fadd_rn(r[6], r[7])));
}

__global__ __launch_bounds__(256) void k_bnorm(const float* __restrict__ cb,
                                               float* __restrict__ bn) {
  __shared__ float rows[64][257];
  int tid = threadIdx.x;
  int c0 = blockIdx.x * 64;
  for (int r = 0; r < 64; ++r)
    rows[r][tid] = cb[(size_t)(c0 + r) * 256 + tid];
  __syncthreads();
  if (tid < 64) {
    float a = np_pairwise128_sq(&rows[tid][0], 1);
    float b = np_pairwise128_sq(&rows[tid][128], 1);
    bn[c0 + tid] = __fadd_rn(a, b);
  }
}

__global__ __launch_bounds__(256) void k_anorm(const float* __restrict__ ze,
                                               float* __restrict__ an) {
  int p = blockIdx.x * 256 + threadIdx.x;
  int b = p >> 10, hw = p & 1023;
  const float* base = ze + (size_t)b * 262144 + hw;
  float a = np_pairwise128_sq(base, 1024);
  float b2 = np_pairwise128_sq(base + 128 * 1024, 1024);
  an[p] = __fadd_rn(a, b2);
}

__global__ __launch_bounds__(256) void k_bmax(const float* __restrict__ bn,
                                              float* __restrict__ bmax) {
  int tid = threadIdx.x;
  float m = 0.f;
  for (int i = tid; i < NVOC; i += 256) m = fmaxf(m, bn[i]);
#pragma unroll
  for (int off = 32; off; off >>= 1) m = fmaxf(m, __shfl_xor(m, off));
  __shared__ float w4[4];
  if ((tid & 63) == 0) w4[tid >> 6] = m;
  __syncthreads();
  if (tid == 0)
    bmax[0] = sqrtf(fmaxf(fmaxf(w4[0], w4[1]), fmaxf(w4[2], w4[3])));
}

// ze [16][256][1024] fp32 -> zebf (bf16) AND zef (fp32), both [16384][256]
__global__ __launch_bounds__(256) void k_cvt_ze(const float* __restrict__ ze,
                                                short* __restrict__ zebf,
                                                float* __restrict__ zef) {
  __shared__ float t[64][132];
  int tid = threadIdx.x;
  int p0 = blockIdx.x * 64;
  int b = p0 >> 10, hw0 = p0 & 1023;
  const float* src = ze + (size_t)b * 262144 + hw0;
  for (int half = 0; half < 2; ++half) {
    if (half) __syncthreads();
    {
      int hw = tid & 63, cq = tid >> 6;
#pragma unroll
      for (int i = 0; i < 32; ++i) {
        int cl = i * 4 + cq;
        t[hw][cl] = src[(size_t)(half * 128 + cl) * 1024 + hw];
      }
    }
    __syncthreads();
    int r = tid >> 2, cg = tid & 3;
    float* fd = zef + (size_t)(p0 + r) * 256 + half * 128 + cg * 32;
    short* bd = zebf + (size_t)(p0 + r) * 256 + half * 128 + cg * 32;
#pragma unroll
    for (int s = 0; s < 8; ++s) {
      float4 v = *reinterpret_cast<const float4*>(&t[r][cg * 32 + s * 4]);
      *reinterpret_cast<float4*>(fd + s * 4) = v;
    }
#pragma unroll
    for (int s = 0; s < 4; ++s) {
      short8v v8;
#pragma unroll
      for (int e = 0; e < 8; ++e) v8[e] = f2bf(t[r][cg * 32 + s * 8 + e]);
      *reinterpret_cast<short8v*>(bd + s * 8) = v8;
    }
  }
}

__global__ __launch_bounds__(256) void k_cvt_cb(const float* __restrict__ cb,
                                                short* __restrict__ cbbf) {
  size_t i = ((size_t)blockIdx.x * 256 + threadIdx.x) * 8;
  float4 a = *reinterpret_cast<const float4*>(cb + i);
  float4 b = *reinterpret_cast<const float4*>(cb + i + 4);
  short8v v;
  v[0] = f2bf(a.x); v[1] = f2bf(a.y); v[2] = f2bf(a.z); v[3] = f2bf(a.w);
  v[4] = f2bf(b.x); v[5] = f2bf(b.y); v[6] = f2bf(b.z); v[7] = f2bf(b.w);
  *reinterpret_cast<short8v*>(cbbf + i) = v;
}

// bf16 MFMA distance GEMM, 256x256 tile, 8 waves (2Mx4N), BK=64 dbuf.
__global__ __launch_bounds__(512, 2) void k_gemm(const short* __restrict__ zebf,
                                                 const short* __restrict__ cbbf,
                                                 const float* __restrict__ bn,
                                                 float* __restrict__ wsmin) {
  __shared__ short As[2][16384];
  __shared__ short Bs[2][16384];
  int tid = threadIdx.x;
  int lane = tid & 63, w = tid >> 6;
  int wr = w >> 2, wc = w & 3;
  int g = lane >> 4, r16 = lane & 15;
  int swz = (blockIdx.x & 7) * 256 + (blockIdx.x >> 3);
  int mb = swz & 63, nb = swz >> 6;
  int p0 = mb * 256, n0 = nb * 256;

  floatx4 acc[8][4];
#pragma unroll
  for (int i = 0; i < 8; ++i)
#pragma unroll
    for (int j = 0; j < 4; ++j) acc[i][j] = floatx4{0.f, 0.f, 0.f, 0.f};

  const short* Aq = zebf + (size_t)p0 * 256;
  const short* Bq = cbbf + (size_t)n0 * 256;

  short8v ra[4], rb[4];
  int srow[4], sc16[4];
#pragma unroll
  for (int s = 0; s < 4; ++s) {
    int cid = tid + s * 512;
    srow[s] = cid >> 3;
    sc16[s] = cid & 7;
  }

#define LOADK(kt)                                                              \
  {                                                                            \
    _Pragma("unroll") for (int s = 0; s < 4; ++s) {                            \
      ra[s] = *reinterpret_cast<const short8v*>(                               \
          Aq + (size_t)srow[s] * 256 + (kt) * 64 + sc16[s] * 8);               \
      rb[s] = *reinterpret_cast<const short8v*>(                               \
          Bq + (size_t)srow[s] * 256 + (kt) * 64 + sc16[s] * 8);               \
    }                                                                          \
  }
#define STOREK(bufi)                                                           \
  {                                                                            \
    _Pragma("unroll") for (int s = 0; s < 4; ++s) {                            \
      int off = srow[s] * 64 + ((sc16[s] ^ (srow[s] & 7)) * 8);                \
      *reinterpret_cast<short8v*>(&As[bufi][off]) = ra[s];                     \
      *reinterpret_cast<short8v*>(&Bs[bufi][off]) = rb[s];                     \
    }                                                                          \
  }

  LOADK(0);
  STOREK(0);
  __syncthreads();

  for (int kt = 0; kt < 4; ++kt) {
    int cur = kt & 1;
    if (kt < 3) LOADK(kt + 1);
#pragma unroll
    for (int ks = 0; ks < 2; ++ks) {
      short8v af[8], bfv[4];
      int c16 = ks * 4 + g;
#pragma unroll
      for (int rf = 0; rf < 8; ++rf) {
        int row = wr * 128 + rf * 16 + r16;
        af[rf] = *reinterpret_cast<const short8v*>(
            &As[cur][row * 64 + ((c16 ^ (row & 7)) * 8)]);
      }
#pragma unroll
      for (int cf = 0; cf < 4; ++cf) {
        int col = wc * 64 + cf * 16 + r16;
        bfv[cf] = *reinterpret_cast<const short8v*>(
            &Bs[cur][col * 64 + ((c16 ^ (col & 7)) * 8)]);
      }
      __builtin_amdgcn_s_setprio(1);
#pragma unroll
      for (int rf = 0; rf < 8; ++rf)
#pragma unroll
        for (int cf = 0; cf < 4; ++cf)
          acc[rf][cf] = __builtin_amdgcn_mfma_f32_16x16x32_bf16(
              af[rf], bfv[cf], acc[rf][cf], 0, 0, 0);
      __builtin_amdgcn_s_setprio(0);
    }
    if (kt < 3) STOREK(cur ^ 1);
    __syncthreads();
  }

  float Bj[4];
#pragma unroll
  for (int cf = 0; cf < 4; ++cf) Bj[cf] = bn[n0 + wc * 64 + cf * 16 + r16];
  float* wout = wsmin + (size_t)(nb * 4 + wc) * NPIX + p0;
#pragma unroll
  for (int rf = 0; rf < 8; ++rf) {
    float rowmin[4];
#pragma unroll
    for (int rr = 0; rr < 4; ++rr) {
      float mv = 3.4e38f;
#pragma unroll
      for (int cf = 0; cf < 4; ++cf)
        mv = fminf(mv, __builtin_fmaf(-2.0f, acc[rf][cf][rr], Bj[cf]));
      rowmin[rr] = mv;
    }
#pragma unroll
    for (int off = 1; off < 16; off <<= 1)
#pragma unroll
      for (int rr = 0; rr < 4; ++rr)
        rowmin[rr] = fminf(rowmin[rr], __shfl_xor(rowmin[rr], off, 16));
    if (r16 == 0) {
#pragma unroll
      for (int rr = 0; rr < 4; ++rr)
        wout[wr * 128 + rf * 16 + g * 4 + rr] = rowmin[rr];
    }
  }
#undef LOADK
#undef STOREK
}

// per-pixel tau + flagged-colblock list; init pk; zero bcnt
__global__ __launch_bounds__(256) void k_reduce(const float* __restrict__ wsmin,
                                                const float* __restrict__ an,
                                                const float* __restrict__ bmax,
                                                int* __restrict__ cnt,
                                                int* __restrict__ cand,
                                                unsigned long long* __restrict__ pk,
                                                int* __restrict__ bcnt) {
  int p = blockIdx.x * 256 + threadIdx.x;
  float mv = 3.4e38f;
#pragma unroll 8
  for (int c = 0; c < 128; ++c) mv = fminf(mv, wsmin[(size_t)c * NPIX + p]);
  float tp = mv + 0.017f * sqrtf(an[p]) * bmax[0] + 2e-4f;
  int n = 0;
  for (int c = 0; c < 128; ++c) {
    if (wsmin[(size_t)c * NPIX + p] <= tp) {
      if (n < 16) cand[p * 16 + n] = c;
      ++n;
    }
  }
  cnt[p] = n;
  pk[p] = ~0ull;
  if (blockIdx.x == 0 && threadIdx.x < 128) bcnt[threadIdx.x] = 0;
}

// scatter pixels into per-colblock buckets
__global__ __launch_bounds__(256) void k_bucket(const int* __restrict__ cnt,
                                                const int* __restrict__ cand,
                                                int* __restrict__ bcnt,
                                                int* __restrict__ blist,
                                                int* __restrict__ ovf) {
  int p = blockIdx.x * 256 + threadIdx.x;
  int n = cnt[p];
  int o = (n > 16) ? 1 : 0;
  if (!o) {
    for (int f = 0; f < n; ++f) {
      int c = cand[p * 16 + f];
      int slot = atomicAdd(&bcnt[c], 1);
      if (slot < BCAP) blist[c * BCAP + slot] = p;
      else o = 1;
    }
  }
  ovf[p] = o;
}

// bucketed exact fp32 rescore: one wg per (colblock, chunk). Codebook block
// staged once in LDS [k][code] (conflict-free); each wave: 4 pixels at a time,
// z-row in registers (coalesced), readlane broadcast, serial k-ascending fmaf.
__global__ __launch_bounds__(256) void k_rescore_b(
    const float* __restrict__ zef, const float* __restrict__ cb,
    const float* __restrict__ an, const float* __restrict__ bn,
    const int* __restrict__ bcnt, const int* __restrict__ blist,
    unsigned long long* __restrict__ pk) {
  int c = blockIdx.x;
  int n = bcnt[c];
  if (n > BCAP) n = BCAP;
  int base = blockIdx.y * CHUNK;
  if (base >= n) return;
  int cnt_here = min(CHUNK, n - base);
  __shared__ float cst[256][64];
  int tid = threadIdx.x;
  {
    int j = tid >> 2, kq = tid & 3;
    const float* src = cb + (size_t)(c * 64 + j) * 256 + kq * 64;
#pragma unroll
    for (int i = 0; i < 16; ++i) {
      float4 v = *reinterpret_cast<const float4*>(src + i * 4);
      int k = kq * 64 + i * 4;
      cst[k][j] = v.x; cst[k + 1][j] = v.y;
      cst[k + 2][j] = v.z; cst[k + 3][j] = v.w;
    }
  }
  __syncthreads();
  int lane = tid & 63, wv = tid >> 6;
  int j_global = c * 64 + lane;
  float bnj = bn[j_global];
  for (int g0 = wv * 4; g0 < cnt_here; g0 += 16) {
    int p[4];
    float4 z[4];
    float ap[4];
#pragma unroll
    for (int g = 0; g < 4; ++g) {
      int idx = base + min(g0 + g, cnt_here - 1);
      p[g] = blist[c * BCAP + idx];
      z[g] = *reinterpret_cast<const float4*>(zef + (size_t)p[g] * 256 + lane * 4);
      ap[g] = an[p[g]];
    }
    float acc0 = 0.f, acc1 = 0.f, acc2 = 0.f, acc3 = 0.f;
#pragma unroll 8
    for (int k4 = 0; k4 < 64; ++k4) {
#pragma unroll
      for (int kk = 0; kk < 4; ++kk) {
        float cv = cst[k4 * 4 + kk][lane];
        float z0 = (kk == 0) ? z[0].x : (kk == 1) ? z[0].y : (kk == 2) ? z[0].z : z[0].w;
        float z1 = (kk == 0) ? z[1].x : (kk == 1) ? z[1].y : (kk == 2) ? z[1].z : z[1].w;
        float z2 = (kk == 0) ? z[2].x : (kk == 1) ? z[2].y : (kk == 2) ? z[2].z : z[2].w;
        float z3 = (kk == 0) ? z[3].x : (kk == 1) ? z[3].y : (kk == 2) ? z[3].z : z[3].w;
        acc0 = __builtin_fmaf(rl(z0, k4), cv, acc0);
        acc1 = __builtin_fmaf(rl(z1, k4), cv, acc1);
        acc2 = __builtin_fmaf(rl(z2, k4), cv, acc2);
        acc3 = __builtin_fmaf(rl(z3, k4), cv, acc3);
      }
    }
    float dv[4] = {acc0, acc1, acc2, acc3};
#pragma unroll
    for (int g = 0; g < 4; ++g) {
      float d = __fsub_rn(__fadd_rn(ap[g], bnj), 2.0f * dv[g]);
      unsigned long long q = packdj(d, j_global);
#pragma unroll
      for (int off = 1; off < 64; off <<= 1) {
        unsigned long long q2 = __shfl_xor(q, off);
        q = q2 < q ? q2 : q;
      }
      if (lane == 0) atomicMin(&pk[p[g]], q);
    }
  }
}

// overflow fallback: wave-cooperative full scan (statistically never runs)
__global__ __launch_bounds__(256) void k_fallback(
    const float* __restrict__ zef, const float* __restrict__ cb,
    const float* __restrict__ an, const float* __restrict__ bn,
    const int* __restrict__ ovf, unsigned long long* __restrict__ pk) {
  int tid = threadIdx.x;
  int p = blockIdx.x * 4 + (tid >> 6);
  if (!ovf[p]) return;
  int lane = tid & 63;
  float ap = an[p];
  const float* zr = zef + (size_t)p * 256;
  unsigned long long best = ~0ull;
  for (int j = lane; j < NVOC; j += 64) {
    const float* cr = cb + (size_t)j * 256;
    float acc = 0.f;
    for (int k = 0; k < 256; ++k) acc = __builtin_fmaf(zr[k], cr[k], acc);
    float d = __fsub_rn(__fadd_rn(ap, bn[j]), 2.0f * acc);
    unsigned long long q = packdj(d, j);
    if (q < best) best = q;
  }
#pragma unroll
  for (int off = 1; off < 64; off <<= 1) {
    unsigned long long q2 = __shfl_xor(best, off);
    best = q2 < best ? q2 : best;
  }
  if (lane == 0) atomicMin(&pk[p], best);
}

__global__ __launch_bounds__(256) void k_gather(const float* __restrict__ ze,
                                                const float* __restrict__ cb,
                                                const unsigned long long* __restrict__ pk,
                                                float* __restrict__ out_zq,
                                                float* __restrict__ out_idx,
                                                float* __restrict__ part) {
  __shared__ float qrow[64][257];
  __shared__ int sidx[64];
  int tid = threadIdx.x;
  int p0 = blockIdx.x * 64;
  int b = p0 >> 10, hw0 = p0 & 1023;
  if (tid < 64) {
    int bi = (int)(unsigned int)(pk[p0 + tid] & 0xffffffffull);
    sidx[tid] = bi;
    out_idx[p0 + tid] = (float)bi;
  }
  __syncthreads();
  for (int r = 0; r < 64; ++r)
    qrow[r][tid] = cb[(size_t)sidx[r] * 256 + tid];
  __syncthreads();
  float lsum = 0.f;
  size_t zbase = (size_t)b * 262144 + hw0;
#pragma unroll 4
  for (int i = 0; i < 64; ++i) {
    int px = tid & 63;
    int c = i * 4 + (tid >> 6);
    float qv = qrow[px][c];
    size_t gi = zbase + (size_t)c * 1024 + px;
    float zev = ze[gi];
    out_zq[gi] = __fadd_rn(zev, __fsub_rn(qv, zev));
    float d = zev - qv;
    lsum = __builtin_fmaf(d, d, lsum);
  }
#pragma unroll
  for (int off = 32; off; off >>= 1) lsum += __shfl_xor(lsum, off, 64);
  __shared__ float wsum[4];
  if ((tid & 63) == 0) wsum[tid >> 6] = lsum;
  __syncthreads();
  if (tid == 0) part[blockIdx.x] = (wsum[0] + wsum[1]) + (wsum[2] + wsum[3]);
}

__global__ __launch_bounds__(256) void k_final(const float* __restrict__ part,
                                               float* __restrict__ out0) {
  int tid = threadIdx.x;
  float s = part[tid];
#pragma unroll
  for (int off = 32; off; off >>= 1) s += __shfl_xor(s, off, 64);
  __shared__ float wsum[4];
  if ((tid & 63) == 0) wsum[tid >> 6] = s;
  __syncthreads();
  if (tid == 0)
    out0[0] = 1.25f * ((wsum[0] + wsum[1]) + (wsum[2] + wsum[3])) / 4194304.0f;
}

extern "C" void kernel_launch(void* const* d_in, const int* in_sizes, int n_in,
                              void* d_out, int out_size, void* d_ws, size_t ws_size,
                              hipStream_t stream) {
  const float* ze = (const float*)d_in[0];
  const float* cb = (const float*)d_in[1];
  float* out = (float*)d_out;
  char* ws = (char*)d_ws;
  short* zebf = (short*)(ws + WS_ZEBF);
  short* cbbf = (short*)(ws + WS_CBBF);
  float* zef = (float*)(ws + WS_ZEF);
  float* bn = (float*)(ws + WS_BN);
  float* an = (float*)(ws + WS_AN);
  float* wsmin = (float*)(ws + WS_MIN);
  int* cnt = (int*)(ws + WS_CNT);
  int* cand = (int*)(ws + WS_CAND);
  int* blist = (int*)(ws + WS_BLIST);
  int* bcnt = (int*)(ws + WS_BCNT);
  int* ovf = (int*)(ws + WS_OVF);
  unsigned long long* pk = (unsigned long long*)(ws + WS_PK);
  float* bmax = (float*)(ws + WS_BMAX);
  float* part = (float*)(ws + WS_PART);
  float* out_loss = out;
  float* out_zq = out + 1;
  float* out_idx = out + 1 + 4194304;

  k_cvt_ze<<<256, 256, 0, stream>>>(ze, zebf, zef);
  k_cvt_cb<<<1024, 256, 0, stream>>>(cb, cbbf);
  k_bnorm<<<128, 256, 0, stream>>>(cb, bn);
  k_anorm<<<64, 256, 0, stream>>>(ze, an);
  k_bmax<<<1, 256, 0, stream>>>(bn, bmax);
  k_gemm<<<2048, 512, 0, stream>>>(zebf, cbbf, bn, wsmin);
  k_reduce<<<64, 256, 0, stream>>>(wsmin, an, bmax, cnt, cand, pk, bcnt);
  k_bucket<<<64, 256, 0, stream>>>(cnt, cand, bcnt, blist, ovf);
  k_rescore_b<<<dim3(128, BCAP / CHUNK), 256, 0, stream>>>(zef, cb, an, bn,
                                                           bcnt, blist, pk);
  k_fallback<<<4096, 256, 0, stream>>>(zef, cb, an, bn, ovf, pk);
  k_gather<<<256, 256, 0, stream>>>(ze, cb, pk, out_zq, out_idx, part);
  k_final<<<1, 256, 0, stream>>>(part, out_loss);
}